// Round 6
// baseline (27.809 us; speedup 1.0000x reference)
//
#include <hip/hip_runtime.h>

#define NS 128   // samples per ray
#define NF 32    // features

// ---------------- pass 1: compact valid ray indices ----------------
__global__ __launch_bounds__(256)
void compact_kernel(const int* __restrict__ valid, int n_rays,
                    int* __restrict__ counter, int* __restrict__ list)
{
    const int i = blockIdx.x * 256 + threadIdx.x;
    const int lane = threadIdx.x & 63;
    const bool v = (i < n_rays) && (valid[i] != 0);
    const unsigned long long mask = __ballot(v);
    const int cnt = __popcll(mask);
    int base = 0;
    if (lane == 0 && cnt) base = atomicAdd(counter, cnt);
    base = __shfl(base, 0, 64);
    if (v) {
        const int pos = __popcll(mask & ((1ull << lane) - 1ull));
        list[base + pos] = i;
    }
}

// ---------------- pass 2: process only valid rays, evenly spread ----------------
// 4096 waves grid-stride the compacted list -> every CU gets ~count/256 rays.
// d_out was zeroed by memsetAsync, so invalid rays need no writes at all.
__global__ __launch_bounds__(256)
void volren_kernel(const float* __restrict__ depths,   // [n_rays, NS]
                   const float* __restrict__ sigma,    // [n_rays, NS]
                   const float* __restrict__ feats,    // [n_rays, NS, NF]
                   const int*   __restrict__ list,     // [count] valid ray ids
                   const int*   __restrict__ counter,  // [1] count
                   float* __restrict__ out_feats,      // [n_rays, NF]
                   float* __restrict__ out_depth,      // [n_rays]
                   float* __restrict__ out_ws,         // [n_rays]
                   float* __restrict__ out_alpha)      // [n_rays]
{
    const int lane  = threadIdx.x & 63;
    const int gwave = blockIdx.x * 4 + (threadIdx.x >> 6);
    const int nwaves = gridDim.x * 4;
    const int count = counter[0];

    const int j = lane >> 3;       // sample-sub index in [0,8)
    const int q = lane & 7;        // float4 quad index in [0,8)

    for (int idx = gwave; idx < count; idx += nwaves) {
        const int ray = list[idx];

        // ---------- issue scan inputs first (vmcnt retires in order) ----------
        const float* dp = depths + (size_t)ray * NS;
        const float* sp = sigma  + (size_t)ray * NS;
        float d_lo = dp[lane];
        float d_hi = dp[lane + 64];
        float s_lo = sp[lane];
        float s_hi = sp[lane + 64];

        // ---------- issue the feats stream: 16 x float4 / lane ----------
        const float4* fptr = (const float4*)(feats + (size_t)ray * NS * NF);
        float4 v0[8], v1[8];
        #pragma unroll
        for (int it = 0; it < 8; ++it)
            v0[it] = fptr[(it * 8 + j) * 8 + q];
        #pragma unroll
        for (int it = 0; it < 8; ++it)
            v1[it] = fptr[((it + 8) * 8 + j) * 8 + q];

        // ---------- phase 1: free energy + wave-wide inclusive scan ----------
        float d_lo_nb = __shfl(d_lo, (lane + 1) & 63, 64);
        float d_hi_nb = __shfl(d_hi, (lane + 1) & 63, 64);
        float d64     = __shfl(d_hi, 0, 64);
        float d_lo_n  = (lane == 63) ? d64  : d_lo_nb;
        float d_hi_n  = (lane == 63) ? d_hi : d_hi_nb;   // last dist = 0

        float fe_lo = (d_lo_n - d_lo) * s_lo;
        float fe_hi = (d_hi_n - d_hi) * s_hi;

        float c_lo = fe_lo;
        #pragma unroll
        for (int off = 1; off < 64; off <<= 1) {
            float t = __shfl_up(c_lo, off, 64);
            if (lane >= off) c_lo += t;
        }
        float tot_lo = __shfl(c_lo, 63, 64);
        float c_hi = fe_hi;
        #pragma unroll
        for (int off = 1; off < 64; off <<= 1) {
            float t = __shfl_up(c_hi, off, 64);
            if (lane >= off) c_hi += t;
        }
        c_hi += tot_lo;

        // w = alpha * exp(fe - cum) = exp(fe - cum) - exp(-cum)
        float w_lo = expf(fe_lo - c_lo) - expf(-c_lo);
        float w_hi = expf(fe_hi - c_hi) - expf(-c_hi);
        float a_lo = 1.0f - expf(-fe_lo);
        float a_hi = 1.0f - expf(-fe_hi);

        // scalar reductions: depth, alpha, weight-sum (overlap feats flight)
        float dsum = w_lo * d_lo + w_hi * d_hi;
        float asum = w_lo * a_lo + w_hi * a_hi;
        float wsum = w_lo + w_hi;
        #pragma unroll
        for (int m = 1; m < 64; m <<= 1) {
            dsum += __shfl_xor(dsum, m, 64);
            asum += __shfl_xor(asum, m, 64);
            wsum += __shfl_xor(wsum, m, 64);
        }
        if (lane == 0) {
            out_depth[ray] = dsum;
            out_ws[ray]    = wsum;
            out_alpha[ray] = asum;
        }

        // ---------- phase 2: feats contraction (weights via in-wave shuffle) ----------
        float4 acc = make_float4(0.f, 0.f, 0.f, 0.f);
        #pragma unroll
        for (int it = 0; it < 8; ++it) {
            const float w = __shfl(w_lo, it * 8 + j, 64);
            acc.x += w * v0[it].x;
            acc.y += w * v0[it].y;
            acc.z += w * v0[it].z;
            acc.w += w * v0[it].w;
        }
        #pragma unroll
        for (int it = 0; it < 8; ++it) {
            const float w = __shfl(w_hi, it * 8 + j, 64);
            acc.x += w * v1[it].x;
            acc.y += w * v1[it].y;
            acc.z += w * v1[it].z;
            acc.w += w * v1[it].w;
        }
        // reduce across the 8 sample-sub lanes (stride 8)
        #pragma unroll
        for (int m = 8; m < 64; m <<= 1) {
            acc.x += __shfl_xor(acc.x, m, 64);
            acc.y += __shfl_xor(acc.y, m, 64);
            acc.z += __shfl_xor(acc.z, m, 64);
            acc.w += __shfl_xor(acc.w, m, 64);
        }
        if (j == 0)
            ((float4*)(out_feats + (size_t)ray * NF))[q] = acc;
    }
}

extern "C" void kernel_launch(void* const* d_in, const int* in_sizes, int n_in,
                              void* d_out, int out_size, void* d_ws, size_t ws_size,
                              hipStream_t stream) {
    const float* depths = (const float*)d_in[0];   // sampled_depths [B,R,S]
    const float* sigma  = (const float*)d_in[1];   // sigma          [B,R,S]
    const float* feats  = (const float*)d_in[2];   // feats          [B,R,S,F]
    // d_in[3] = max_depths (unused by the reference math)
    const int*   valid  = (const int*)d_in[4];     // valid_rays     [B,R]

    const int n_rays = in_sizes[4];                // B*R = 8192

    float* out       = (float*)d_out;
    float* out_feats = out;                               // [n_rays, NF]
    float* out_depth = out + (size_t)n_rays * NF;         // [n_rays]
    float* out_ws    = out_depth + n_rays;                // [n_rays]
    float* out_alpha = out_ws + n_rays;                   // [n_rays]

    // workspace: [0..15] counter (16B-aligned pad), [16..] compacted list
    int* counter = (int*)d_ws;
    int* list    = (int*)((char*)d_ws + 16);

    // zero counter + all outputs (invalid rays then need no writes at all)
    hipMemsetAsync(counter, 0, 16, stream);
    hipMemsetAsync(d_out, 0, (size_t)out_size * sizeof(float), stream);

    compact_kernel<<<(n_rays + 255) / 256, 256, 0, stream>>>(valid, n_rays,
                                                             counter, list);

    // 1024 blocks x 4 waves = 4096 waves: each CU gets ~count/256 rays -> balanced
    volren_kernel<<<1024, 256, 0, stream>>>(depths, sigma, feats, list, counter,
                                            out_feats, out_depth, out_ws,
                                            out_alpha);
}